// Round 1
// baseline (554.759 us; speedup 1.0000x reference)
//
#include <hip/hip_runtime.h>

// Problem constants (from reference setup_inputs)
constexpr int BN = 24;   // batch*num_cams
constexpr int C  = 256;  // channels
constexpr int IH = 16;   // input H
constexpr int IW = 44;   // input W
constexpr int OH = 128;  // output H
constexpr int OW = 128;  // output W

// Mathematical identity: einsum('nchw,ndhw->nchw', img, softmax(logits, d))
//   = img * sum_d softmax = img. So the kernel is purely the bilinear
// upsample of img_feat; depth_logits never needs to be read.
//
// Half-pixel-center bilinear (align_corners=False), clamp-to-edge.
// Each thread produces one float4 of output (4 consecutive x). A 64-lane
// wave writes 256 contiguous floats = 2 full output rows -> perfectly
// coalesced 1 KB stores. Input planes are tiny (2816 B per (n,c)) and
// re-read through L1/L2 broadcast.
__global__ __launch_bounds__(256) void lss_bilinear_kernel(
    const float* __restrict__ in, float* __restrict__ out) {
    const int i = blockIdx.x * blockDim.x + threadIdx.x;
    // total float4 elements = BN*C*OH*OW/4 = 25,165,824 ; grid covers exactly
    const int x4 = (i & 31) << 2;        // 0..124, step 4 (OW/4 = 32)
    const int y  = (i >> 5) & (OH - 1);  // 0..127
    const int nc = i >> 12;              // n*C + c, 0..6143

    // --- vertical source coordinate (scale = IH/OH = 0.125) ---
    const float ys = (y + 0.5f) * 0.125f - 0.5f;
    const float yf = floorf(ys);
    const float wy = ys - yf;
    int y0 = (int)yf;
    int y1 = y0 + 1;
    y0 = min(max(y0, 0), IH - 1);
    y1 = min(max(y1, 0), IH - 1);

    const float* __restrict__ row0 = in + ((size_t)nc * IH + y0) * IW;
    const float* __restrict__ row1 = in + ((size_t)nc * IH + y1) * IW;

    float4 o;
    float* op = &o.x;
#pragma unroll
    for (int j = 0; j < 4; ++j) {
        const int x = x4 + j;
        // horizontal source coordinate (scale = IW/OW = 0.34375)
        const float xs = (x + 0.5f) * 0.34375f - 0.5f;
        const float xf = floorf(xs);
        const float wx = xs - xf;
        int x0 = (int)xf;
        int x1 = x0 + 1;
        x0 = min(max(x0, 0), IW - 1);
        x1 = min(max(x1, 0), IW - 1);

        const float v00 = row0[x0];
        const float v01 = row0[x1];
        const float v10 = row1[x0];
        const float v11 = row1[x1];
        const float top = v00 + (v01 - v00) * wx;
        const float bot = v10 + (v11 - v10) * wx;
        op[j] = top + (bot - top) * wy;
    }

    reinterpret_cast<float4*>(out)[i] = o;
}

extern "C" void kernel_launch(void* const* d_in, const int* in_sizes, int n_in,
                              void* d_out, int out_size, void* d_ws, size_t ws_size,
                              hipStream_t stream) {
    const float* img_feat = (const float*)d_in[0];
    // d_in[1] (depth_logits) is mathematically a no-op: softmax sums to 1
    // over the reduced axis -> einsum result == img_feat.
    float* out = (float*)d_out;

    constexpr int total_f4 = BN * C * OH * OW / 4;  // 25,165,824
    constexpr int block = 256;
    constexpr int grid = total_f4 / block;          // 98,304 (exact)
    lss_bilinear_kernel<<<grid, block, 0, stream>>>(img_feat, out);
}